// Round 14
// baseline (302.963 us; speedup 1.0000x reference)
//
#include <hip/hip_runtime.h>
#include <hip/hip_bf16.h>
#include <math.h>

#define NN 262144
#define NCC 65536

typedef __bf16 bf16x8 __attribute__((ext_vector_type(8)));
typedef float f32x4 __attribute__((ext_vector_type(4)));

#define RAW_BARRIER() __builtin_amdgcn_s_barrier()
#define LGKM0() asm volatile("s_waitcnt lgkmcnt(0)" ::: "memory")

// ---------- setup: blocks 0..47 precompute Mt; blocks 48..175 zero flags ----------
__global__ __launch_bounds__(256) void k_setup(const float* __restrict__ w_orig,
                                               const float* __restrict__ w_prop,
                                               const float* __restrict__ w_ctx,
                                               const float* __restrict__ W_fuse,
                                               __bf16* __restrict__ Mt,
                                               unsigned char* __restrict__ flags) {
    __shared__ float Wl[64 * 65];
    __shared__ float wl[64 * 65];
    int b = blockIdx.x;
    int t = threadIdx.x;
    if (b >= 48) {   // zero 2*NN flag bytes: 128 blocks * 256 threads * 16B
        ((uint4*)flags)[(b - 48) * 256 + t] = make_uint4(0u, 0u, 0u, 0u);
        return;
    }
    int seg = b >> 4, rem = b & 15;
    int ot = rem >> 2, mt = rem & 3;
    const float* wseg = seg == 0 ? w_orig : (seg == 1 ? w_prop : w_ctx);
    int to = (t & 15) * 4, tm = (t >> 4) * 4;
    float acc[4][4] = {};
    for (int kc = 0; kc < 4; ++kc) {
        __syncthreads();
        for (int i = 0; i < 16; ++i) {
            int f = i * 256 + t;
            int row = f >> 6, col = f & 63;
            Wl[row * 65 + col] = W_fuse[(size_t)(ot * 64 + row) * 768 + seg * 256 + kc * 64 + col];
            wl[row * 65 + col] = wseg[(size_t)(mt * 64 + row) * 256 + kc * 64 + col];
        }
        __syncthreads();
        for (int k = 0; k < 64; ++k) {
            float wo[4], wm2[4];
#pragma unroll
            for (int i = 0; i < 4; ++i) wo[i] = Wl[(to + i) * 65 + k];
#pragma unroll
            for (int j = 0; j < 4; ++j) wm2[j] = wl[(tm + j) * 65 + k];
#pragma unroll
            for (int i = 0; i < 4; ++i)
#pragma unroll
                for (int j = 0; j < 4; ++j) acc[i][j] += wo[i] * wm2[j];
        }
    }
    for (int i = 0; i < 4; ++i)
        for (int j = 0; j < 4; ++j) {
            int o = ot * 64 + to + i;
            int g = seg * 256 + mt * 64 + tm + j;
            Mt[(size_t)o * 768 + g] = (__bf16)acc[i][j];
        }
}

__global__ void k_setflags(const int* __restrict__ idxp, const int* __restrict__ idxc,
                           unsigned char* fp, unsigned char* fc) {
    int j = blockIdx.x * blockDim.x + threadIdx.x;
    if (j < NCC) { fp[idxp[j]] = 1; fc[idxc[j]] = 1; }
}

__device__ inline bf16x8 cvt8(f32x4 a, f32x4 b) {
    bf16x8 w;
    w[0] = (__bf16)a[0]; w[1] = (__bf16)a[1]; w[2] = (__bf16)a[2]; w[3] = (__bf16)a[3];
    w[4] = (__bf16)b[0]; w[5] = (__bf16)b[1]; w[6] = (__bf16)b[2]; w[7] = (__bf16)b[3];
    return w;
}

#define MFMA __builtin_amdgcn_mfma_f32_16x16x32_bf16

// ---------- one kernel; super-tiles of 4 blocks: {copy hp slab s, copy hc slab s, gemm 2s, gemm 2s+1} ----------
// Copy slab s = rows [512s, 512s+512); gemm tile b gathers rows ~[256b, 256b+256) (sorted idx) ->
// the 4 blocks of a super-tile touch the same address range and are dispatch-adjacent -> L3/L2 reuse.
__global__ __launch_bounds__(512, 4) void k_main(const float* __restrict__ hp,
                                                 const float* __restrict__ hc,
                                                 const float* __restrict__ horig,
                                                 const __bf16* __restrict__ Mt,
                                                 const float* __restrict__ bfuse,
                                                 const float* __restrict__ bias,
                                                 const int* __restrict__ idxp,
                                                 const int* __restrict__ idxc,
                                                 const unsigned char* __restrict__ fp,
                                                 const unsigned char* __restrict__ fc,
                                                 float* __restrict__ out0,
                                                 float* __restrict__ out1) {
    __shared__ __align__(16) char smem[40960];
    int g = blockIdx.x;
    int s = g >> 2, sub = g & 3;
    int t = threadIdx.x;

    if (sub < 2) {
        // ================= copy role: 512-row slab s of table `sub` =================
        int tbl = sub;
        const unsigned char* F = tbl ? fc : fp;
        const float* S = tbl ? hc : hp;
        float* D = tbl ? out1 : out0;
        int r0 = s * 512;
#pragma unroll
        for (int gg = 0; gg < 8; ++gg) {
            unsigned char fl[8];
            f32x4 v[8];
#pragma unroll
            for (int i = 0; i < 8; ++i) {
                int gl = (gg * 8 + i) * 512 + t;
                fl[i] = F[r0 + (gl >> 6)];
            }
#pragma unroll
            for (int i = 0; i < 8; ++i) {
                int gl = (gg * 8 + i) * 512 + t;
                int r = r0 + (gl >> 6), slot = gl & 63;
                v[i] = *(const f32x4*)(S + (size_t)(fl[i] ? 0 : r) * 256 + slot * 4);
            }
#pragma unroll
            for (int i = 0; i < 8; ++i) {
                int gl = (gg * 8 + i) * 512 + t;
                int r = r0 + (gl >> 6), slot = gl & 63;
                if (!fl[i]) *(f32x4*)(D + (size_t)r * 256 + slot * 4) = v[i];
            }
        }
        return;
    }

    // ================= gemm role: tile bid = 2s + (sub-2), 64x256 output =================
    int bid = s * 2 + (sub - 2);
    __bf16* Al = (__bf16*)smem;            // 8 KB, swizzled
    __bf16* Bl = (__bf16*)(smem + 8192);   // 32 KB, swizzled
    int jbase = bid * 64;
    int lane = t & 63, wid = t >> 6;
    int wm = wid >> 2, wn = wid & 3;
    int l15 = lane & 15, lq = lane >> 4;

    // A staging: thread -> (row ar, 8-f32 slot aslot)
    int ar = t >> 3, aslot = t & 7;
    int jr = jbase + ar;
    const float* rowp0 = horig + (size_t)jr * 256 + aslot * 8;
    const float* rowp1 = hp + (size_t)idxp[jr] * 256 + aslot * 8;
    const float* rowp2 = hc + (size_t)idxc[jr] * 256 + aslot * 8;

    // B staging: thread -> (row bo, 32-elem half bkp)
    int bo = t >> 1, bkp = t & 1;
    const __bf16* bsrc = Mt + (size_t)bo * 768 + bkp * 32;

    f32x4 a0[2], a1[2];
    bf16x8 vb[4];
    {   // prologue: A chunks 0,1; B chunk 0
        a0[0] = *(const f32x4*)(rowp0);       a1[0] = *(const f32x4*)(rowp0 + 4);
        a0[1] = *(const f32x4*)(rowp0 + 64);  a1[1] = *(const f32x4*)(rowp0 + 68);
#pragma unroll
        for (int i = 0; i < 4; ++i) vb[i] = *(const bf16x8*)(bsrc + i * 8);
    }

    f32x4 acc[2][4] = {};

#pragma unroll
    for (int c = 0; c < 12; ++c) {
        int sreg = c & 1;
        RAW_BARRIER();   // prev compute's LDS reads already consumed into regs -> safe to overwrite
        *(bf16x8*)&Al[ar * 64 + ((aslot ^ (ar & 7)) << 3)] = cvt8(a0[sreg], a1[sreg]);
#pragma unroll
        for (int i = 0; i < 4; ++i) {
            int slot = bkp * 4 + i;
            *(bf16x8*)&Bl[bo * 64 + ((slot ^ (bo & 7)) << 3)] = vb[i];
        }
        // prefetch: B for c+1 (L2, 1-deep), A for c+2 (2-deep)
        if (c < 11) {
#pragma unroll
            for (int i = 0; i < 4; ++i) vb[i] = *(const bf16x8*)(bsrc + (c + 1) * 64 + i * 8);
        }
        if (c < 10) {
            int cn = c + 2;
            int seg = cn >> 2, ko = (cn & 3) * 64;
            const float* sp = (seg == 0 ? rowp0 : (seg == 1 ? rowp1 : rowp2)) + ko;
            a0[sreg] = *(const f32x4*)(sp);
            a1[sreg] = *(const f32x4*)(sp + 4);
        }
        LGKM0();         // ds_writes visible; global prefetches stay in flight across the barrier
        RAW_BARRIER();
        // compute chunk c
#pragma unroll
        for (int ks = 0; ks < 2; ++ks) {
            bf16x8 af[2], bfr[4];
            int kslot = ks * 4 + lq;
#pragma unroll
            for (int mi = 0; mi < 2; ++mi) {
                int r = wm * 32 + mi * 16 + l15;
                af[mi] = *(const bf16x8*)&Al[r * 64 + ((kslot ^ (r & 7)) << 3)];
            }
#pragma unroll
            for (int ni = 0; ni < 4; ++ni) {
                int o = wn * 64 + ni * 16 + l15;
                bfr[ni] = *(const bf16x8*)&Bl[o * 64 + ((kslot ^ (o & 7)) << 3)];
            }
#pragma unroll
            for (int mi = 0; mi < 2; ++mi)
#pragma unroll
                for (int ni = 0; ni < 4; ++ni)
                    acc[mi][ni] = MFMA(af[mi], bfr[ni], acc[mi][ni], 0, 0, 0);
        }
    }

    // ---- epilogue: tanh + bias, per-wave LDS transpose, f32x4 contiguous scattered stores ----
    float bfv[4], biv[4];
#pragma unroll
    for (int ni = 0; ni < 4; ++ni) {
        int o = wn * 64 + ni * 16 + l15;
        bfv[ni] = bfuse[o];
        biv[ni] = bias[o];
    }
    LGKM0();
    RAW_BARRIER();   // all LDS reads of main loop consumed; reuse Bl region as scratch
    float* scr = (float*)(smem + 8192 + wid * 4096);   // per-wave 16x64 f32
#pragma unroll
    for (int mi = 0; mi < 2; ++mi) {
#pragma unroll
        for (int ni = 0; ni < 4; ++ni)
#pragma unroll
            for (int rr = 0; rr < 4; ++rr) {
                float v = tanhf(acc[mi][ni][rr] + bfv[ni]) + biv[ni];
                scr[(lq * 4 + rr) * 64 + ni * 16 + l15] = v;
            }
        // intra-wave ds ordering: own writes visible to own reads
#pragma unroll
        for (int rnd = 0; rnd < 4; ++rnd) {
            int rr2 = rnd * 4 + lq;
            int j = jbase + wm * 32 + mi * 16 + rr2;
            int gp = idxp[j], gc = idxc[j];
            f32x4 v = *(const f32x4*)&scr[rr2 * 64 + l15 * 4];
            *(f32x4*)(out0 + (size_t)gp * 256 + wn * 64 + l15 * 4) = v;
            *(f32x4*)(out1 + (size_t)gc * 256 + wn * 64 + l15 * 4) = v;
        }
    }
}

extern "C" void kernel_launch(void* const* d_in, const int* in_sizes, int n_in,
                              void* d_out, int out_size, void* d_ws, size_t ws_size,
                              hipStream_t stream) {
    const float* hp     = (const float*)d_in[0];
    const float* hc     = (const float*)d_in[1];
    const float* horig  = (const float*)d_in[2];
    const float* w_orig = (const float*)d_in[3];
    const float* w_prop = (const float*)d_in[4];
    const float* w_ctx  = (const float*)d_in[5];
    const float* W_fuse = (const float*)d_in[6];
    const float* bfuse  = (const float*)d_in[7];
    const float* bias   = (const float*)d_in[8];
    const int* idxp     = (const int*)d_in[9];
    const int* idxc     = (const int*)d_in[10];
    float* out0 = (float*)d_out;
    float* out1 = out0 + (size_t)NN * 256;

    char* ws = (char*)d_ws;
    __bf16* Mt = (__bf16*)ws;                              // 256*768*2 = 393216 B
    unsigned char* fp = (unsigned char*)(ws + 393216);     // NN bytes
    unsigned char* fc = fp + NN;                           // NN bytes

    k_setup<<<176, 256, 0, stream>>>(w_orig, w_prop, w_ctx, W_fuse, Mt, fp);
    k_setflags<<<NCC / 256, 256, 0, stream>>>(idxp, idxc, fp, fc);
    k_main<<<2048, 512, 0, stream>>>(hp, hc, horig, Mt, bfuse, bias,
                                     idxp, idxc, fp, fc, out0, out1);
}

// Round 15
// 297.450 us; speedup vs baseline: 1.0185x; 1.0185x over previous
//
#include <hip/hip_runtime.h>
#include <hip/hip_bf16.h>
#include <math.h>

#define NN 262144
#define NCC 65536

typedef __bf16 bf16x8 __attribute__((ext_vector_type(8)));
typedef __bf16 bf16x4 __attribute__((ext_vector_type(4)));
typedef float f32x4 __attribute__((ext_vector_type(4)));

#define RAW_BARRIER() __builtin_amdgcn_s_barrier()
#define LGKM0() asm volatile("s_waitcnt lgkmcnt(0)" ::: "memory")
#define MFMA __builtin_amdgcn_mfma_f32_16x16x32_bf16

// ---------- setup: blocks 0..47 precompute Mt; blocks 48..175 zero flags ----------
__global__ __launch_bounds__(256) void k_setup(const float* __restrict__ w_orig,
                                               const float* __restrict__ w_prop,
                                               const float* __restrict__ w_ctx,
                                               const float* __restrict__ W_fuse,
                                               __bf16* __restrict__ Mt,
                                               unsigned char* __restrict__ flags) {
    __shared__ float Wl[64 * 65];
    __shared__ float wl[64 * 65];
    int b = blockIdx.x;
    int t = threadIdx.x;
    if (b >= 48) {   // zero 2*NN flag bytes: 128 blocks * 256 threads * 16B
        ((uint4*)flags)[(b - 48) * 256 + t] = make_uint4(0u, 0u, 0u, 0u);
        return;
    }
    int seg = b >> 4, rem = b & 15;
    int ot = rem >> 2, mt = rem & 3;
    const float* wseg = seg == 0 ? w_orig : (seg == 1 ? w_prop : w_ctx);
    int to = (t & 15) * 4, tm = (t >> 4) * 4;
    float acc[4][4] = {};
    for (int kc = 0; kc < 4; ++kc) {
        __syncthreads();
        for (int i = 0; i < 16; ++i) {
            int f = i * 256 + t;
            int row = f >> 6, col = f & 63;
            Wl[row * 65 + col] = W_fuse[(size_t)(ot * 64 + row) * 768 + seg * 256 + kc * 64 + col];
            wl[row * 65 + col] = wseg[(size_t)(mt * 64 + row) * 256 + kc * 64 + col];
        }
        __syncthreads();
        for (int k = 0; k < 64; ++k) {
            float wo[4], wm2[4];
#pragma unroll
            for (int i = 0; i < 4; ++i) wo[i] = Wl[(to + i) * 65 + k];
#pragma unroll
            for (int j = 0; j < 4; ++j) wm2[j] = wl[(tm + j) * 65 + k];
#pragma unroll
            for (int i = 0; i < 4; ++i)
#pragma unroll
                for (int j = 0; j < 4; ++j) acc[i][j] += wo[i] * wm2[j];
        }
    }
    for (int i = 0; i < 4; ++i)
        for (int j = 0; j < 4; ++j) {
            int o = ot * 64 + to + i;
            int g = seg * 256 + mt * 64 + tm + j;
            Mt[(size_t)o * 768 + g] = (__bf16)acc[i][j];
        }
}

__global__ void k_setflags(const int* __restrict__ idxp, const int* __restrict__ idxc,
                           unsigned char* fp, unsigned char* fc) {
    int j = blockIdx.x * blockDim.x + threadIdx.x;
    if (j < NCC) { fp[idxp[j]] = 1; fc[idxc[j]] = 1; }
}

// ---------- one kernel, two block roles: even = copy slab, odd = gemm tile ----------
__global__ __launch_bounds__(512, 4) void k_main(const float* __restrict__ hp,
                                                 const float* __restrict__ hc,
                                                 const float* __restrict__ horig,
                                                 const __bf16* __restrict__ Mt,
                                                 const float* __restrict__ bfuse,
                                                 const float* __restrict__ bias,
                                                 const int* __restrict__ idxp,
                                                 const int* __restrict__ idxc,
                                                 const unsigned char* __restrict__ fp,
                                                 const unsigned char* __restrict__ fc,
                                                 float* __restrict__ out0,
                                                 float* __restrict__ out1) {
    __shared__ __align__(16) char smem[65536];   // A: 4 chunk-bufs x 8KB [0,32768) | B: [32768,65536); epilogue reuses all 64KB
    int bid = blockIdx.x >> 1;
    int t = threadIdx.x;

    if (!(blockIdx.x & 1)) {
        // ================= copy role: 512 rows of one table (champion verbatim) =================
        int tbl = bid >= 512;
        const unsigned char* F = tbl ? fc : fp;
        const float* S = tbl ? hc : hp;
        float* D = tbl ? out1 : out0;
        int r0 = (tbl ? bid - 512 : bid) * 512;
#pragma unroll
        for (int g = 0; g < 8; ++g) {
            unsigned char fl[8];
            f32x4 v[8];
#pragma unroll
            for (int i = 0; i < 8; ++i) {
                int gl = (g * 8 + i) * 512 + t;
                fl[i] = F[r0 + (gl >> 6)];
            }
#pragma unroll
            for (int i = 0; i < 8; ++i) {
                int gl = (g * 8 + i) * 512 + t;
                int r = r0 + (gl >> 6), slot = gl & 63;
                v[i] = *(const f32x4*)(S + (size_t)(fl[i] ? 0 : r) * 256 + slot * 4);
            }
#pragma unroll
            for (int i = 0; i < 8; ++i) {
                int gl = (g * 8 + i) * 512 + t;
                int r = r0 + (gl >> 6), slot = gl & 63;
                if (!fl[i]) *(f32x4*)(D + (size_t)r * 256 + slot * 4) = v[i];
            }
        }
        return;
    }

    // ================= gemm role: 64x256 tile, 8 waves, seg-outer 1KB-burst A staging =================
    __bf16* Bl = (__bf16*)(smem + 32768);
    int jbase = bid * 64;
    int lane = t & 63, wid = t >> 6;
    int wm = wid >> 2, wn = wid & 3;
    int l15 = lane & 15, lq = lane >> 4;

    // wave stages rows wid*8+i (full 1KB per row per instr); same rows stored in epilogue
    int ip[8], ic[8];
#pragma unroll
    for (int i = 0; i < 8; ++i) {
        int j = jbase + wid * 8 + i;
        ip[i] = idxp[j];
        ic[i] = idxc[j];
    }

    // B staging (champion): thread -> (row bo, 32-elem half bkp)
    int bo = t >> 1, bkp = t & 1;
    const __bf16* bsrc = Mt + (size_t)bo * 768 + bkp * 32;

    // prologue: seg0 A rows (horig, dense) + B chunk 0
    f32x4 v[8];
#pragma unroll
    for (int i = 0; i < 8; ++i)
        v[i] = *(const f32x4*)(horig + (size_t)(jbase + wid * 8 + i) * 256 + lane * 4);
    bf16x8 vb[4];
#pragma unroll
    for (int i = 0; i < 4; ++i) vb[i] = *(const bf16x8*)(bsrc + i * 8);

    f32x4 acc[2][4] = {};

    // A staging address components: lane covers f32 k = lane*4..+3 -> chunk lane>>4, granule (l15)>>1, half lane&1
    int acb = (lane >> 4) * 8192;
    int as8 = l15 >> 1;
    int ahb = (lane & 1) * 8;

#pragma unroll
    for (int seg = 0; seg < 3; ++seg) {
        RAW_BARRIER();   // prev seg's A reads + prev chunk's B reads done (reads consumed pre-barrier)
        // write A-seg: all 4 chunk buffers, one 1KB-sourced row per instr
#pragma unroll
        for (int i = 0; i < 8; ++i) {
            int r = wid * 8 + i;
            bf16x4 w;
            w[0] = (__bf16)v[i][0]; w[1] = (__bf16)v[i][1];
            w[2] = (__bf16)v[i][2]; w[3] = (__bf16)v[i][3];
            *(bf16x4*)(smem + acb + r * 128 + (((as8 ^ (r & 7)) << 4)) + ahb) = w;
        }
        // issue next seg's A loads: 1KB bursts, in flight across this seg's 4 chunks
        if (seg < 2) {
#pragma unroll
            for (int i = 0; i < 8; ++i) {
                const float* src = (seg == 0) ? hp + (size_t)ip[i] * 256 : hc + (size_t)ic[i] * 256;
                v[i] = *(const f32x4*)(src + lane * 4);
            }
        }
#pragma unroll
        for (int c = 0; c < 4; ++c) {
            int cg = seg * 4 + c;
            if (c) RAW_BARRIER();   // prev chunk's B reads done (A region stable)
#pragma unroll
            for (int i = 0; i < 4; ++i) {
                int slot = bkp * 4 + i;
                *(bf16x8*)&Bl[bo * 64 + ((slot ^ (bo & 7)) << 3)] = vb[i];
            }
            if (cg < 11) {
#pragma unroll
                for (int i = 0; i < 4; ++i) vb[i] = *(const bf16x8*)(bsrc + (cg + 1) * 64 + i * 8);
            }
            LGKM0();         // ds_writes visible; global prefetches stay in flight
            RAW_BARRIER();
            // compute chunk (A from chunk buffer c, champion read formulas)
#pragma unroll
            for (int ks = 0; ks < 2; ++ks) {
                bf16x8 af[2], bfr[4];
                int kslot = ks * 4 + lq;
#pragma unroll
                for (int mi = 0; mi < 2; ++mi) {
                    int r = wm * 32 + mi * 16 + l15;
                    af[mi] = *(const bf16x8*)(smem + c * 8192 + r * 128 + ((kslot ^ (r & 7)) << 4));
                }
#pragma unroll
                for (int ni = 0; ni < 4; ++ni) {
                    int o = wn * 64 + ni * 16 + l15;
                    bfr[ni] = *(const bf16x8*)&Bl[o * 64 + ((kslot ^ (o & 7)) << 3)];
                }
#pragma unroll
                for (int mi = 0; mi < 2; ++mi)
#pragma unroll
                    for (int ni = 0; ni < 4; ++ni)
                        acc[mi][ni] = MFMA(af[mi], bfr[ni], acc[mi][ni], 0, 0, 0);
            }
        }
    }

    // ---- epilogue: full-block LDS transpose (64x256 f32 = 64KB) -> 1KB row stores ----
    float bfv[4], biv[4];
#pragma unroll
    for (int ni = 0; ni < 4; ++ni) {
        int o = wn * 64 + ni * 16 + l15;
        bfv[ni] = bfuse[o];
        biv[ni] = bias[o];
    }
    LGKM0();
    RAW_BARRIER();   // all main-loop LDS reads consumed; reuse full smem as scratch
    float* scr = (float*)smem;
#pragma unroll
    for (int mi = 0; mi < 2; ++mi)
#pragma unroll
        for (int ni = 0; ni < 4; ++ni)
#pragma unroll
            for (int rr = 0; rr < 4; ++rr) {
                float val = tanhf(acc[mi][ni][rr] + bfv[ni]) + biv[ni];
                int jr2 = wm * 32 + mi * 16 + lq * 4 + rr;
                scr[jr2 * 256 + wn * 64 + ni * 16 + l15] = val;
            }
    LGKM0();
    RAW_BARRIER();   // all waves' transpose writes visible
#pragma unroll
    for (int i = 0; i < 8; ++i) {
        int jj = wid * 8 + i;
        f32x4 val = *(const f32x4*)(smem + jj * 1024 + lane * 16);
        *(f32x4*)(out0 + (size_t)ip[i] * 256 + lane * 4) = val;
        *(f32x4*)(out1 + (size_t)ic[i] * 256 + lane * 4) = val;
    }
}

extern "C" void kernel_launch(void* const* d_in, const int* in_sizes, int n_in,
                              void* d_out, int out_size, void* d_ws, size_t ws_size,
                              hipStream_t stream) {
    const float* hp     = (const float*)d_in[0];
    const float* hc     = (const float*)d_in[1];
    const float* horig  = (const float*)d_in[2];
    const float* w_orig = (const float*)d_in[3];
    const float* w_prop = (const float*)d_in[4];
    const float* w_ctx  = (const float*)d_in[5];
    const float* W_fuse = (const float*)d_in[6];
    const float* bfuse  = (const float*)d_in[7];
    const float* bias   = (const float*)d_in[8];
    const int* idxp     = (const int*)d_in[9];
    const int* idxc     = (const int*)d_in[10];
    float* out0 = (float*)d_out;
    float* out1 = out0 + (size_t)NN * 256;

    char* ws = (char*)d_ws;
    __bf16* Mt = (__bf16*)ws;                              // 256*768*2 = 393216 B
    unsigned char* fp = (unsigned char*)(ws + 393216);     // NN bytes
    unsigned char* fc = fp + NN;                           // NN bytes

    k_setup<<<176, 256, 0, stream>>>(w_orig, w_prop, w_ctx, W_fuse, Mt, fp);
    k_setflags<<<NCC / 256, 256, 0, stream>>>(idxp, idxc, fp, fc);
    k_main<<<2048, 512, 0, stream>>>(hp, hc, horig, Mt, bfuse, bias,
                                     idxp, idxc, fp, fc, out0, out1);
}